// Round 1
// 175.252 us; speedup vs baseline: 1.0196x; 1.0196x over previous
//
#include <hip/hip_runtime.h>

// Problem: y[b,c,0,h,w] = x[b,c,0,h,w]
//          y[b,c,n,h,w] = 0.3*x[b,c,n,h,w] + 0.7*y[b,c,n-1,h,w]
// Shapes: x,y = [4, 3, 32, 256, 256] fp32. Recurrence along axis 2 (N=32).
//
// v2: segmented scan. The v1 decomposition (1 thread per chain) gave only
// 768 blocks = 12 waves/CU and ~3 loads in flight (VGPR=32) -> latency-bound
// at 2.4 TB/s. Split each chain into 4 segments of 8 frames:
//   - 4x threads (3072 blocks) -> occupancy cap moves from grid to VGPR (full 32 waves/CU)
//   - 8 independent frame-loads issued per thread before any use (deep MLP)
//   - segment carries closed via LDS + one __syncthreads():
//       carry(s) = e[s-1] + 0.7^8 * e[s-2] + 0.7^16 * e[s-3]
//       y[n]     = p[n] + 0.7^(n+1) * carry            (carry = 0 for seg 0)
// Traffic unchanged: x read once, y written once.

constexpr int   NFR = 32;               // frames (recurrence length)
constexpr int   HW4 = (256 * 256) / 4;  // float4 elements per frame-plane (16384)
constexpr int   FPS = 8;                // frames per segment
constexpr int   CPB = 64;               // chains per block (block = 64 chains x 4 segs)
constexpr float WF  = 0.3f;
constexpr float OMW = 0.7f;

// 0.7^k, compile-time
constexpr float P1  = 0.7f;
constexpr float P2  = P1 * 0.7f;
constexpr float P3  = P2 * 0.7f;
constexpr float P4  = P3 * 0.7f;
constexpr float P5  = P4 * 0.7f;
constexpr float P6  = P5 * 0.7f;
constexpr float P7  = P6 * 0.7f;
constexpr float P8  = P7 * 0.7f;
constexpr float P16 = P8 * P8;

__global__ __launch_bounds__(256) void recfilt_kernel(const float4* __restrict__ x,
                                                      float4* __restrict__ y) {
    const int tid = threadIdx.x;
    const int c   = tid & (CPB - 1);   // chain slot within block
    const int seg = tid >> 6;          // 0..3, wave-uniform (64 lanes per seg)
    const int q   = blockIdx.x * CPB + c;      // global chain id [0, 196608)
    const int bc  = q >> 14;                   // q / HW4
    const int hw  = q & (HW4 - 1);             // q % HW4
    const long base = (long)bc * (NFR * HW4) + (long)seg * (FPS * HW4) + hw;

    // ---- issue all 8 frame loads up front (independent -> 8 in flight) ----
    float4 v0 = x[base + 0 * HW4];
    float4 v1 = x[base + 1 * HW4];
    float4 v2 = x[base + 2 * HW4];
    float4 v3 = x[base + 3 * HW4];
    float4 v4 = x[base + 4 * HW4];
    float4 v5 = x[base + 5 * HW4];
    float4 v6 = x[base + 6 * HW4];
    float4 v7 = x[base + 7 * HW4];

    // ---- local prefix. seg 0 frame 0: y[0] = x[0] (leave v0). seg>0: zero IC ----
    if (seg != 0) {
        v0.x *= WF; v0.y *= WF; v0.z *= WF; v0.w *= WF;
    }
#define STEP(a, b)                                      \
    b.x = WF * b.x + OMW * a.x; b.y = WF * b.y + OMW * a.y; \
    b.z = WF * b.z + OMW * a.z; b.w = WF * b.w + OMW * a.w;
    STEP(v0, v1) STEP(v1, v2) STEP(v2, v3) STEP(v3, v4)
    STEP(v4, v5) STEP(v5, v6) STEP(v6, v7)
#undef STEP

    // ---- publish segment-end partials, close the carry chain ----
    __shared__ float4 lend[3][CPB];
    if (seg < 3) lend[seg][c] = v7;
    __syncthreads();

    float4 carry = make_float4(0.f, 0.f, 0.f, 0.f);
    if (seg == 1) {
        carry = lend[0][c];
    } else if (seg == 2) {
        const float4 e0 = lend[0][c], e1 = lend[1][c];
        carry.x = fmaf(P8, e0.x, e1.x);
        carry.y = fmaf(P8, e0.y, e1.y);
        carry.z = fmaf(P8, e0.z, e1.z);
        carry.w = fmaf(P8, e0.w, e1.w);
    } else if (seg == 3) {
        const float4 e0 = lend[0][c], e1 = lend[1][c], e2 = lend[2][c];
        carry.x = fmaf(P16, e0.x, fmaf(P8, e1.x, e2.x));
        carry.y = fmaf(P16, e0.y, fmaf(P8, e1.y, e2.y));
        carry.z = fmaf(P16, e0.z, fmaf(P8, e1.z, e2.z));
        carry.w = fmaf(P16, e0.w, fmaf(P8, e1.w, e2.w));
    }

    // ---- y[n] = p[n] + 0.7^(n+1) * carry ; store 8 frames ----
#define OUT(n, v, pk)                                   \
    {                                                   \
        float4 o;                                       \
        o.x = fmaf(pk, carry.x, v.x);                   \
        o.y = fmaf(pk, carry.y, v.y);                   \
        o.z = fmaf(pk, carry.z, v.z);                   \
        o.w = fmaf(pk, carry.w, v.w);                   \
        y[base + n * HW4] = o;                          \
    }
    OUT(0, v0, P1) OUT(1, v1, P2) OUT(2, v2, P3) OUT(3, v3, P4)
    OUT(4, v4, P5) OUT(5, v5, P6) OUT(6, v6, P7) OUT(7, v7, P8)
#undef OUT
}

extern "C" void kernel_launch(void* const* d_in, const int* in_sizes, int n_in,
                              void* d_out, int out_size, void* d_ws, size_t ws_size,
                              hipStream_t stream) {
    const float4* x = (const float4*)d_in[0];
    float4*       y = (float4*)d_out;
    const int chains = 12 * HW4;                 // 196,608
    const int grid   = chains / CPB;             // 3072 blocks, 256 thr each
    recfilt_kernel<<<grid, 256, 0, stream>>>(x, y);
}

// Round 2
// 175.117 us; speedup vs baseline: 1.0204x; 1.0008x over previous
//
#include <hip/hip_runtime.h>

// Problem: y[b,c,0,h,w] = x[b,c,0,h,w]
//          y[b,c,n,h,w] = 0.3*x[b,c,n,h,w] + 0.7*y[b,c,n-1,h,w]
// Shapes: x,y = [4, 3, 32, 256, 256] fp32. Recurrence along axis 2 (N=32).
//
// v3 = v2 (segmented scan, 4 segs x 8 frames, LDS carry closure) plus:
//   - __launch_bounds__(256, 8): force VGPR <= 64 so 8 waves/SIMD fit.
//     v2 likely sat at 5-6 waves/SIMD (8 live float4 + 64-bit addressing),
//     which is why 4x grid parallelism bought almost nothing.
//   - 32-bit indexing (max float4 index = 6.29M < 2^31/16) to cut address VGPRs.
//   - nontemporal stores for y: the lines are dead after this kernel (the
//     harness re-poisons them), so don't allocate them in L2/L3 -> the x
//     read stream keeps the cache. Expect FETCH_SIZE 49 MB -> ~40 MB.
// Numerics identical to v2 (absmax 0.0078125, passed).

typedef float vf4 __attribute__((ext_vector_type(4)));

constexpr int   NFR = 32;               // frames (recurrence length)
constexpr int   HW4 = (256 * 256) / 4;  // float4 per frame-plane (16384 = 2^14)
constexpr int   FPS = 8;                // frames per segment
constexpr int   CPB = 64;               // chains per block (block = 64 chains x 4 segs)
constexpr float WF  = 0.3f;
constexpr float OMW = 0.7f;

constexpr float P1  = 0.7f;
constexpr float P2  = P1 * 0.7f;
constexpr float P3  = P2 * 0.7f;
constexpr float P4  = P3 * 0.7f;
constexpr float P5  = P4 * 0.7f;
constexpr float P6  = P5 * 0.7f;
constexpr float P7  = P6 * 0.7f;
constexpr float P8  = P7 * 0.7f;
constexpr float P16 = P8 * P8;

__global__ __launch_bounds__(256, 8) void recfilt_kernel(const vf4* __restrict__ x,
                                                         vf4* __restrict__ y) {
    const int tid = threadIdx.x;
    const int c   = tid & (CPB - 1);   // chain slot within block
    const int seg = tid >> 6;          // 0..3, wave-uniform
    const int q   = blockIdx.x * CPB + c;      // global chain id [0, 196608)
    const int bc  = q >> 14;                   // q / HW4
    const int hw  = q & (HW4 - 1);             // q % HW4
    const int base = bc * (NFR * HW4) + seg * (FPS * HW4) + hw;   // fits in int32

    // ---- 8 independent frame loads up front ----
    vf4 v0 = x[base + 0 * HW4];
    vf4 v1 = x[base + 1 * HW4];
    vf4 v2 = x[base + 2 * HW4];
    vf4 v3 = x[base + 3 * HW4];
    vf4 v4 = x[base + 4 * HW4];
    vf4 v5 = x[base + 5 * HW4];
    vf4 v6 = x[base + 6 * HW4];
    vf4 v7 = x[base + 7 * HW4];

    // ---- local prefix. seg 0 frame 0: y[0]=x[0] (leave v0). seg>0: zero IC ----
    if (seg != 0) v0 *= WF;
    v1 = WF * v1 + OMW * v0;
    v2 = WF * v2 + OMW * v1;
    v3 = WF * v3 + OMW * v2;
    v4 = WF * v4 + OMW * v3;
    v5 = WF * v5 + OMW * v4;
    v6 = WF * v6 + OMW * v5;
    v7 = WF * v7 + OMW * v6;

    // ---- publish segment-end partials, close the carry chain ----
    __shared__ vf4 lend[3][CPB];
    if (seg < 3) lend[seg][c] = v7;
    __syncthreads();

    vf4 carry = (vf4)(0.0f);
    if (seg == 1) {
        carry = lend[0][c];
    } else if (seg == 2) {
        carry = lend[1][c] + P8 * lend[0][c];
    } else if (seg == 3) {
        carry = (lend[2][c] + P8 * lend[1][c]) + P16 * lend[0][c];
    }

    // ---- y[n] = p[n] + 0.7^(n+1) * carry ; nontemporal stores ----
    vf4 o0 = v0 + P1 * carry;  __builtin_nontemporal_store(o0, &y[base + 0 * HW4]);
    vf4 o1 = v1 + P2 * carry;  __builtin_nontemporal_store(o1, &y[base + 1 * HW4]);
    vf4 o2 = v2 + P3 * carry;  __builtin_nontemporal_store(o2, &y[base + 2 * HW4]);
    vf4 o3 = v3 + P4 * carry;  __builtin_nontemporal_store(o3, &y[base + 3 * HW4]);
    vf4 o4 = v4 + P5 * carry;  __builtin_nontemporal_store(o4, &y[base + 4 * HW4]);
    vf4 o5 = v5 + P6 * carry;  __builtin_nontemporal_store(o5, &y[base + 5 * HW4]);
    vf4 o6 = v6 + P7 * carry;  __builtin_nontemporal_store(o6, &y[base + 6 * HW4]);
    vf4 o7 = v7 + P8 * carry;  __builtin_nontemporal_store(o7, &y[base + 7 * HW4]);
}

extern "C" void kernel_launch(void* const* d_in, const int* in_sizes, int n_in,
                              void* d_out, int out_size, void* d_ws, size_t ws_size,
                              hipStream_t stream) {
    const vf4* x = (const vf4*)d_in[0];
    vf4*       y = (vf4*)d_out;
    const int chains = 12 * HW4;                 // 196,608
    const int grid   = chains / CPB;             // 3072 blocks, 256 thr each
    recfilt_kernel<<<grid, 256, 0, stream>>>(x, y);
}